// Round 1
// baseline (945.537 us; speedup 1.0000x reference)
//
#include <hip/hip_runtime.h>
#include <cstdint>

typedef unsigned short u16;
typedef __attribute__((ext_vector_type(8))) __bf16 bf16x8;
typedef __attribute__((ext_vector_type(4))) float f32x4;

#define N_DIM 4096

__device__ __forceinline__ u16 f2bf(float f) {
    union { float f; unsigned u; } c; c.f = f;
    unsigned u = c.u;
    u += 0x7FFFu + ((u >> 16) & 1u);   // round-nearest-even
    return (u16)(u >> 16);
}

__device__ __forceinline__ void gl_lds16(const u16* g, u16* l) {
    __builtin_amdgcn_global_load_lds(
        (const __attribute__((address_space(1))) void*)g,
        (__attribute__((address_space(3))) void*)l, 16, 0, 0);
}

// ---------------------------------------------------------------------------
// Kernel 1: band table. bnd[n*9 + (off+4)] = M[n, n+off] (0 if out of range).
// spdiags layout: segments off=-4..4, lengths N-|off|, concatenated.
// off>=0: M[n,n+off] = s[base+n];  off<0: M[n,n+off] = s[base+n+off].
// ---------------------------------------------------------------------------
__global__ void band_kernel(const float* __restrict__ s,
                            const float* __restrict__ s_pre,
                            const float* __restrict__ gate,
                            float* __restrict__ bnd) {
    int n = blockIdx.x * blockDim.x + threadIdx.x;
    if (n >= N_DIM) return;
    float sig = 1.0f / (1.0f + __expf(-gate[0]));
    const int base[9] = {0, 4092, 8185, 12279, 16374, 20470, 24565, 28659, 32752};
    #pragma unroll
    for (int o = 0; o < 9; ++o) {
        int off = o - 4;
        int col = n + off;
        float val = 0.0f;
        if (col >= 0 && col < N_DIM) {
            int idx = (off >= 0) ? (base[o] + n) : (base[o] + n + off);
            val = s[idx] * sig;
        }
        if (off == 0) val += s_pre[n];
        bnd[n * 9 + o] = val;
    }
}

// ---------------------------------------------------------------------------
// Kernel 2: P[din, n] = sum_off bnd[n][off] * v[n+off, din], stored bf16,
// row-major [4096, 4096] (K=n contiguous). Tile transpose through LDS.
// ---------------------------------------------------------------------------
__global__ void band_combine_t(const float* __restrict__ v,
                               const float* __restrict__ bnd,
                               u16* __restrict__ P) {
    __shared__ float tile[32][33];
    int n0 = blockIdx.x * 32;
    int d0 = blockIdx.y * 32;
    int tx = threadIdx.x;   // 0..31  -> d (coalesced v reads)
    int ty = threadIdx.y;   // 0..7
    #pragma unroll
    for (int i = 0; i < 4; ++i) {
        int nl = ty + 8 * i;
        int n = n0 + nl;
        int d = d0 + tx;
        float acc = 0.0f;
        #pragma unroll
        for (int o = 0; o < 9; ++o) {
            int src = n + o - 4;
            float w = bnd[n * 9 + o];
            float vv = ((unsigned)src < (unsigned)N_DIM) ? v[(size_t)src * N_DIM + d] : 0.0f;
            acc += w * vv;
        }
        tile[nl][tx] = acc;
    }
    __syncthreads();
    #pragma unroll
    for (int i = 0; i < 4; ++i) {
        int dl = ty + 8 * i;
        P[(size_t)(d0 + dl) * N_DIM + (n0 + tx)] = f2bf(tile[tx][dl]);
    }
}

// ---------------------------------------------------------------------------
// Kernel 3: fp32 -> bf16 elementwise (float4 vectorized; nElem % 4 == 0)
// ---------------------------------------------------------------------------
__global__ void cvt_bf16(const float* __restrict__ in, u16* __restrict__ out, int nElem4) {
    int i = blockIdx.x * blockDim.x + threadIdx.x;
    if (i >= nElem4) return;
    float4 f = ((const float4*)in)[i];
    ushort4 o;
    o.x = f2bf(f.x); o.y = f2bf(f.y); o.z = f2bf(f.z); o.w = f2bf(f.w);
    ((ushort4*)out)[i] = o;
}

// ---------------------------------------------------------------------------
// TN GEMM (m97 structure): C[m,n] = sum_k A[m,k]*B[n,k], A/B bf16 row-major,
// 128x128 block tile, BK=32, 4 waves in 2x2, each wave 64x64 via 4x4 MFMA
// 16x16x32 tiles. global_load_lds width=16 staging, ds_read_b128 fragments.
// ---------------------------------------------------------------------------
template <bool OUT_BF16>
__global__ __launch_bounds__(256)
void gemm_tn(const u16* __restrict__ A, const u16* __restrict__ B,
             float* __restrict__ Cf, u16* __restrict__ Cb,
             int M, int N, int K) {
    __shared__ u16 As[128 * 32];
    __shared__ u16 Bs[128 * 32];
    const int tid = threadIdx.x;
    const int lane = tid & 63;
    const int wave = tid >> 6;
    const int wm = wave >> 1;       // 0..1
    const int wn = wave & 1;        // 0..1
    const long m0 = (long)blockIdx.y * 128;
    const long n0 = (long)blockIdx.x * 128;

    const u16* Ab = A + m0 * K;
    const u16* Bb = B + n0 * K;

    f32x4 acc[4][4];
    #pragma unroll
    for (int i = 0; i < 4; ++i)
        #pragma unroll
        for (int j = 0; j < 4; ++j)
            acc[i][j] = (f32x4){0.f, 0.f, 0.f, 0.f};

    const int row = tid >> 2;          // 0..63 (4 x 16B chunks per 32-k row)
    const int kc  = (tid & 3) * 8;

    const int ml = lane & 15;
    const int kq = (lane >> 4) * 8;

    for (int kt = 0; kt < K; kt += 32) {
        __syncthreads();
        gl_lds16(Ab + (long)row * K + kt + kc,        &As[tid * 8]);
        gl_lds16(Ab + (long)(row + 64) * K + kt + kc, &As[2048 + tid * 8]);
        gl_lds16(Bb + (long)row * K + kt + kc,        &Bs[tid * 8]);
        gl_lds16(Bb + (long)(row + 64) * K + kt + kc, &Bs[2048 + tid * 8]);
        __syncthreads();   // compiler emits s_waitcnt vmcnt(0) before s_barrier

        bf16x8 af[4], bfr[4];
        #pragma unroll
        for (int i = 0; i < 4; ++i)
            af[i] = *(const bf16x8*)&As[(wm * 64 + i * 16 + ml) * 32 + kq];
        #pragma unroll
        for (int i = 0; i < 4; ++i)
            bfr[i] = *(const bf16x8*)&Bs[(wn * 64 + i * 16 + ml) * 32 + kq];

        #pragma unroll
        for (int mi = 0; mi < 4; ++mi)
            #pragma unroll
            for (int ni = 0; ni < 4; ++ni)
                acc[mi][ni] = __builtin_amdgcn_mfma_f32_16x16x32_bf16(
                    af[mi], bfr[ni], acc[mi][ni], 0, 0, 0);
    }

    // Epilogue. D layout: col = lane&15, row = (lane>>4)*4 + reg  [m89]
    const int cn = lane & 15;
    const int rg = lane >> 4;
    #pragma unroll
    for (int mi = 0; mi < 4; ++mi) {
        #pragma unroll
        for (int ni = 0; ni < 4; ++ni) {
            const long mb = m0 + wm * 64 + mi * 16 + rg * 4;
            const long nn = n0 + wn * 64 + ni * 16 + cn;
            #pragma unroll
            for (int r = 0; r < 4; ++r) {
                const long off = (mb + r) * N + nn;
                if (OUT_BF16) Cb[off] = f2bf(acc[mi][ni][r]);
                else          Cf[off] = acc[mi][ni][r];
            }
        }
    }
}

// ---------------------------------------------------------------------------
// out = x @ ((M v)^T u^T)  computed as:
//   bnd   = band table of M                       (tiny)
//   P     = (M v)^T   bf16  [D_IN, N]             (banded combine + transpose)
//   Ubf   = bf16(u)         [D_OUT, N]
//   Xbf   = bf16(x)         [B*S, D_IN]
//   Wt    = weight^T = u M v = GEMM_TN(Ubf, P)    [D_OUT, D_IN] bf16
//   out   = GEMM_TN(Xbf, Wt)                      [B*S, D_OUT] fp32
// ---------------------------------------------------------------------------
extern "C" void kernel_launch(void* const* d_in, const int* in_sizes, int n_in,
                              void* d_out, int out_size, void* d_ws, size_t ws_size,
                              hipStream_t stream) {
    const float* x     = (const float*)d_in[0];   // [4, 2048, 4096]
    const float* u     = (const float*)d_in[1];   // [4096, 4096]
    const float* v     = (const float*)d_in[2];   // [4096, 4096]
    const float* s_pre = (const float*)d_in[3];   // [4096]
    const float* s     = (const float*)d_in[4];   // [36844]
    const float* gate  = (const float*)d_in[5];   // [1]
    // d_in[6]=row, d_in[7]=col: reconstructed analytically, unused.
    float* out = (float*)d_out;                    // [8192, 4096]

    const int BS = 8192;        // 4*2048
    const size_t NN = (size_t)N_DIM * N_DIM;       // 16777216

    char* ws = (char*)d_ws;
    float* bnd = (float*)ws;                                   // 147 KB
    u16*   P   = (u16*)(ws + (1 << 18));                       // 32 MB
    u16*   Ubf = (u16*)(ws + (1 << 18) + NN * 2);              // 32 MB
    u16*   Wt  = (u16*)(ws + (1 << 18) + NN * 4);              // 32 MB
    u16*   Xbf = (u16*)(ws + (1 << 18) + NN * 6);              // 64 MB

    // 1. band table
    band_kernel<<<16, 256, 0, stream>>>(s, s_pre, gate, bnd);

    // 2. P = (M v)^T in bf16
    band_combine_t<<<dim3(128, 128), dim3(32, 8), 0, stream>>>(v, bnd, P);

    // 3. bf16 casts
    cvt_bf16<<<(int)(NN / 4 / 256), 256, 0, stream>>>(u, Ubf, (int)(NN / 4));
    cvt_bf16<<<(int)((size_t)BS * N_DIM / 4 / 256), 256, 0, stream>>>(
        x, Xbf, (int)((size_t)BS * N_DIM / 4));

    // 4. Wt = Ubf @ P^T   [4096 x 4096], bf16 output
    gemm_tn<true><<<dim3(N_DIM / 128, N_DIM / 128), 256, 0, stream>>>(
        Ubf, P, nullptr, Wt, N_DIM, N_DIM, N_DIM);

    // 5. out = Xbf @ Wt^T  [8192 x 4096], fp32 output
    gemm_tn<false><<<dim3(N_DIM / 128, BS / 128), 256, 0, stream>>>(
        Xbf, Wt, out, nullptr, BS, N_DIM, N_DIM);
}